// Round 1
// baseline (612.256 us; speedup 1.0000x reference)
//
#include <hip/hip_runtime.h>

// ExampleModelSISO: out = x * exclusive_cumsum(x, axis=time)
// x: [B=8, T=4096, D=1024] float32.
//
// R4: single-pass chained scan with decoupled lookback (+ tiny init kernel).
//  - One read of x from HBM, one write of out (nontemporal). No 3-kernel
//    round trip, no part[] re-scan kernel.
//  - Per-(chunk,b,d) state is a packed 64-bit {flag,value} slot accessed with
//    device-scope relaxed atomics (flag+payload atomic together -> no fences).
//  - Atomic ticketing guarantees lookback forward progress regardless of
//    dispatch order / residency (predecessor tickets were taken by blocks
//    that already started; AMD blocks run to completion).
//  - Windowed (4-deep) lookback walk bounds the serial tail.

typedef float vf4 __attribute__((ext_vector_type(4)));

constexpr int B = 8;
constexpr int T = 4096;
constexpr int D = 1024;
constexpr int C = 128;        // chunks along T
constexpr int L = T / C;      // 32 timesteps per chunk
constexpr int THREADS = 256;  // 256 threads * float4 = 1024 = D
constexpr int NCHUNK = B * C; // 1024 blocks

constexpr unsigned FLAG_INVALID = 0u;
constexpr unsigned FLAG_AGG     = 1u;
constexpr unsigned FLAG_PREFIX  = 2u;

// slot index for (chunk c, batch b, feature d): ((c*B + b)*D + d)
// total NCHUNK*D u64 slots = 8 MiB, then a 4-byte ticket counter.

__global__ __launch_bounds__(THREADS)
void init_state(unsigned long long* __restrict__ slots,
                unsigned* __restrict__ counter) {
    const size_t i = (size_t)blockIdx.x * THREADS + threadIdx.x;
    // 1024 blocks * 256 threads * 4 slots = 1,048,576 = NCHUNK*D
#pragma unroll
    for (int k = 0; k < 4; ++k)
        slots[i * 4 + k] = 0ULL;
    if (i == 0) *counter = 0u;
}

__global__ __launch_bounds__(THREADS)
void scan_lookback(const float* __restrict__ x, float* __restrict__ out,
                   unsigned long long* __restrict__ slots,
                   unsigned* __restrict__ counter) {
    // ---- ticket: virtual chunk id in scheduling order (progress guarantee)
    __shared__ unsigned s_ticket;
    if (threadIdx.x == 0) s_ticket = atomicAdd(counter, 1u);
    __syncthreads();
    const unsigned v = s_ticket;
    const int b = (int)(v & (B - 1)); // consecutive tickets spread across b
    const int c = (int)(v >> 3);      // per-b chunk index ascends with ticket
    const int d4 = threadIdx.x * 4;

    const size_t xbase = ((size_t)(b * T + c * L)) * D + d4;

    // ---- phase 1: read own chunk, per-lane column sums
    vf4 agg = (vf4)(0.f);
#pragma unroll 8
    for (int t = 0; t < L; ++t)
        agg += *(const vf4*)(x + xbase + (size_t)t * D);

    // ---- publish aggregate (c==0 publishes its inclusive prefix directly)
    unsigned long long* myslot = slots + ((size_t)c * B + b) * D + d4;
    {
        const unsigned long long f =
            (unsigned long long)(c == 0 ? FLAG_PREFIX : FLAG_AGG) << 32;
#pragma unroll
        for (int j = 0; j < 4; ++j) {
            unsigned long long pk =
                f | (unsigned long long)__float_as_uint(agg[j]);
            __hip_atomic_store(&myslot[j], pk, __ATOMIC_RELAXED,
                               __HIP_MEMORY_SCOPE_AGENT);
        }
    }

    // ---- phase 2: decoupled lookback, window of 4 predecessors per round
    float pref[4] = {0.f, 0.f, 0.f, 0.f};
    if (c > 0) {
        int P = c - 1;        // next predecessor position to resolve
        unsigned pend = 0xFu; // per-j (4 d-lanes) unresolved mask
        unsigned rounds = 0u;
        while (pend) {
            if (++rounds > (1u << 22)) break; // bail out instead of hanging
            unsigned long long sv[4][4];
#pragma unroll
            for (int k = 0; k < 4; ++k) {
                int p = P - k;
                p = p < 0 ? 0 : p; // clamped speculative load; guarded below
                const unsigned long long* ps =
                    slots + ((size_t)p * B + b) * D + d4;
#pragma unroll
                for (int j = 0; j < 4; ++j)
                    sv[k][j] = __hip_atomic_load(&ps[j], __ATOMIC_RELAXED,
                                                 __HIP_MEMORY_SCOPE_AGENT);
            }
            int consumed = 0;
            bool halt = false;
#pragma unroll
            for (int k = 0; k < 4; ++k) {
                const bool active = !halt && (P - k >= 0) && (pend != 0u);
                if (active) {
                    unsigned rdy = 1u;
#pragma unroll
                    for (int j = 0; j < 4; ++j)
                        if ((pend >> j) & 1u)
                            if ((unsigned)(sv[k][j] >> 32) == FLAG_INVALID)
                                rdy = 0u;
                    if (!rdy) {
                        halt = true; // retry this position next round
                    } else {
#pragma unroll
                        for (int j = 0; j < 4; ++j)
                            if ((pend >> j) & 1u) {
                                pref[j] += __uint_as_float(
                                    (unsigned)(sv[k][j] & 0xffffffffULL));
                                if ((unsigned)(sv[k][j] >> 32) == FLAG_PREFIX)
                                    pend &= ~(1u << j);
                            }
                        ++consumed;
                    }
                }
            }
            P -= consumed;
            if (consumed == 0 && pend) __builtin_amdgcn_s_sleep(1);
        }
        // publish own inclusive prefix so successors short-circuit
        const unsigned long long f = (unsigned long long)FLAG_PREFIX << 32;
#pragma unroll
        for (int j = 0; j < 4; ++j) {
            unsigned long long pk =
                f | (unsigned long long)__float_as_uint(pref[j] + agg[j]);
            __hip_atomic_store(&myslot[j], pk, __ATOMIC_RELAXED,
                               __HIP_MEMORY_SCOPE_AGENT);
        }
    }

    // ---- phase 3: re-read own (cache-warm) chunk, scan + multiply, nt-store
    vf4 s;
    s[0] = pref[0]; s[1] = pref[1]; s[2] = pref[2]; s[3] = pref[3];
#pragma unroll 4
    for (int t = 0; t < L; ++t) {
        vf4 vv = *(const vf4*)(x + xbase + (size_t)t * D);
        vf4 o = vv * s;
        s += vv;
        __builtin_nontemporal_store(o, (vf4*)(out + xbase + (size_t)t * D));
    }
}

extern "C" void kernel_launch(void* const* d_in, const int* in_sizes, int n_in,
                              void* d_out, int out_size, void* d_ws,
                              size_t ws_size, hipStream_t stream) {
    const float* x = (const float*)d_in[0];
    float* out = (float*)d_out;
    unsigned long long* slots = (unsigned long long*)d_ws; // 8 MiB
    unsigned* counter =
        (unsigned*)((char*)d_ws + (size_t)NCHUNK * D * sizeof(unsigned long long));

    init_state<<<1024, THREADS, 0, stream>>>(slots, counter);
    scan_lookback<<<NCHUNK, THREADS, 0, stream>>>(x, out, slots, counter);
}

// Round 2
// 485.745 us; speedup vs baseline: 1.2604x; 1.2604x over previous
//
#include <hip/hip_runtime.h>
#include <hip/hip_cooperative_groups.h>

// ExampleModelSISO: out = x * exclusive_cumsum(x, axis=time)
// x: [B=8, T=4096, D=1024] float32.
//
// R5: single cooperative kernel, 3 phases separated by grid.sync().
//  - Lookback (R4) reverted: agent-scope atomic spin livelocked under rocprof
//    and ran at 0.1 GB/s (cross-XCD coherence point is past L2 -> ~900cy/poll).
//  - grid.sync() gives the agent-scope release/acquire ordering for free and
//    costs ~µs, not a spin.
//  - Phase 1: per-(b,chunk) aggregates -> part.   (HBM read of x, 128 MiB)
//  - Phase 2: 32 blocks scan partials (4 MiB), others wait at the barrier.
//  - Phase 3: re-read own chunk (IF$-warm), scan+multiply, nontemporal store.
//  - No workspace init, no flags, single dispatch.

typedef float vf4 __attribute__((ext_vector_type(4)));

namespace cg = cooperative_groups;

constexpr int B = 8;
constexpr int T = 4096;
constexpr int D = 1024;
constexpr int C = 128;       // chunks along T
constexpr int L = T / C;     // 32 timesteps per chunk
constexpr int THREADS = 256; // 256 threads * float4 = 1024 = D
constexpr int BD = B * D;    // 8192 chains
constexpr int NBLK = B * C;  // 1024 blocks

__global__ __launch_bounds__(THREADS)
void fused_scan(const float* __restrict__ x, float* __restrict__ part,
                float* __restrict__ out) {
    cg::grid_group grid = cg::this_grid();

    const int bc = blockIdx.x;
    const int b = bc / C;
    const int c = bc % C;
    const int d4 = threadIdx.x * 4;

    const size_t xbase = ((size_t)(b * T + c * L)) * D + d4;

    // ---- phase 1: per-chunk column aggregates
    vf4 agg = (vf4)(0.f);
#pragma unroll 8
    for (int t = 0; t < L; ++t)
        agg += *(const vf4*)(x + xbase + (size_t)t * D);
    *(vf4*)(part + (size_t)c * BD + b * D + d4) = agg;

    grid.sync();

    // ---- phase 2: exclusive scan of the C partials per chain.
    // 32 blocks * 256 threads = 8192 threads, one per chain.
    if (bc < BD / THREADS) {
        const int j = bc * THREADS + threadIdx.x; // chain id
        float run = 0.f;
        constexpr int TILE = 16;
#pragma unroll
        for (int c0 = 0; c0 < C; c0 += TILE) {
            float v[TILE];
#pragma unroll
            for (int k = 0; k < TILE; ++k)
                v[k] = part[(size_t)(c0 + k) * BD + j];
#pragma unroll
            for (int k = 0; k < TILE; ++k) {
                part[(size_t)(c0 + k) * BD + j] = run;
                run += v[k];
            }
        }
    }

    grid.sync();

    // ---- phase 3: within-chunk exclusive scan seeded by chunk prefix
    vf4 s = *(const vf4*)(part + (size_t)c * BD + b * D + d4);
#pragma unroll 4
    for (int t = 0; t < L; ++t) {
        vf4 v = *(const vf4*)(x + xbase + (size_t)t * D);
        vf4 o = v * s;
        s += v;
        __builtin_nontemporal_store(o, (vf4*)(out + xbase + (size_t)t * D));
    }
}

extern "C" void kernel_launch(void* const* d_in, const int* in_sizes, int n_in,
                              void* d_out, int out_size, void* d_ws,
                              size_t ws_size, hipStream_t stream) {
    const float* x = (const float*)d_in[0];
    float* out = (float*)d_out;
    float* part = (float*)d_ws; // C*B*D*4 = 4 MiB scratch

    void* args[] = {(void*)&x, (void*)&part, (void*)&out};
    hipLaunchCooperativeKernel((const void*)fused_scan, dim3(NBLK),
                               dim3(THREADS), args, 0, stream);
}

// Round 3
// 253.582 us; speedup vs baseline: 2.4144x; 1.9155x over previous
//
#include <hip/hip_runtime.h>

// ExampleModelSISO: out = x * exclusive_cumsum(x, axis=time)
// x: [B=8, T=4096, D=1024] float32, out same shape.
//
// R6: back to the 3-kernel chunked scan (R5's cooperative grid.sync cost
// ~100 µs/barrier on 1024 blocks across 8 XCDs; R4's atomic lookback
// livelocked). Of the 254 µs baseline, ~160 µs is harness re-poison fills;
// our kernels are ~90 µs vs a ~72 µs roofline. This round shaves the slack:
//  - k2: TILE 16->32 (halves serial latency rounds), 128 x 64-thread blocks
//    to spread cross-XCD partial reads over more CUs.
//  - k3: unroll 8 for deeper load ILP against mixed read+write streams.
//  - x stays normally cached (IF$-resident for k3's re-read); out is
//    nontemporal-stored.

typedef float vf4 __attribute__((ext_vector_type(4)));

constexpr int B = 8;
constexpr int T = 4096;
constexpr int D = 1024;
constexpr int C = 128;       // chunks along T
constexpr int L = T / C;     // 32 timesteps per chunk
constexpr int THREADS = 256; // 256 threads * float4 = 1024 = D
constexpr int BD = B * D;    // 8192 chains

// Kernel 1: per-chunk sums. Block = one (b, chunk); thread = 4 consecutive d.
// part layout: part[c][b*D + d]  (chain index = b*D+d)
__global__ __launch_bounds__(THREADS)
void partial_sums(const float* __restrict__ x, float* __restrict__ part) {
    const int bc = blockIdx.x;
    const int b = bc / C;
    const int c = bc % C;
    const int d4 = threadIdx.x * 4;

    const float* px = x + ((size_t)(b * T + c * L)) * D + d4;
    vf4 acc = (vf4)(0.f);
#pragma unroll 8
    for (int t = 0; t < L; ++t) {
        vf4 v = *(const vf4*)(px + (size_t)t * D);
        acc += v;
    }
    *(vf4*)(part + (size_t)c * BD + b * D + d4) = acc;
}

// Kernel 2: exclusive scan of the C chunk sums along c for each chain.
// One thread per chain (8192 threads), 64-thread blocks x 128 to spread
// across CUs. TILE=32 keeps 32 coalesced loads in flight per thread
// (4 latency rounds over C=128 instead of 8).
constexpr int K2_THREADS = 64;
__global__ __launch_bounds__(K2_THREADS)
void scan_partials(float* __restrict__ part) {
    const int j = blockIdx.x * K2_THREADS + threadIdx.x; // chain id, 0..BD-1
    float run = 0.f;
    constexpr int TILE = 32;
#pragma unroll
    for (int c0 = 0; c0 < C; c0 += TILE) {
        float v[TILE];
#pragma unroll
        for (int k = 0; k < TILE; ++k)
            v[k] = part[(size_t)(c0 + k) * BD + j];
#pragma unroll
        for (int k = 0; k < TILE; ++k) {
            part[(size_t)(c0 + k) * BD + j] = run;
            run += v[k];
        }
    }
}

// Kernel 3: within-chunk exclusive scan seeded by chunk prefix; out = x * s_prev.
__global__ __launch_bounds__(THREADS)
void scan_mul(const float* __restrict__ x, const float* __restrict__ part,
              float* __restrict__ out) {
    const int bc = blockIdx.x;
    const int b = bc / C;
    const int c = bc % C;
    const int d4 = threadIdx.x * 4;

    const size_t base = ((size_t)(b * T + c * L)) * D + d4;
    vf4 s = *(const vf4*)(part + (size_t)c * BD + b * D + d4);
#pragma unroll 8
    for (int t = 0; t < L; ++t) {
        vf4 v = *(const vf4*)(x + base + (size_t)t * D);
        vf4 o = v * s;
        s += v;
        __builtin_nontemporal_store(o, (vf4*)(out + base + (size_t)t * D));
    }
}

extern "C" void kernel_launch(void* const* d_in, const int* in_sizes, int n_in,
                              void* d_out, int out_size, void* d_ws, size_t ws_size,
                              hipStream_t stream) {
    const float* x = (const float*)d_in[0];
    float* out = (float*)d_out;
    float* part = (float*)d_ws; // C*B*D*4 = 4 MiB of scratch

    partial_sums<<<B * C, THREADS, 0, stream>>>(x, part);
    scan_partials<<<BD / K2_THREADS, K2_THREADS, 0, stream>>>(part);
    scan_mul<<<B * C, THREADS, 0, stream>>>(x, part, out);
}

// Round 4
// 249.138 us; speedup vs baseline: 2.4575x; 1.0178x over previous
//
#include <hip/hip_runtime.h>

// ExampleModelSISO: out = x * exclusive_cumsum(x, axis=time)
// x: [B=8, T=4096, D=1024] float32, out same shape.
//
// R7: 2-kernel chunked scan — k2 (partial-scan) fused into k3.
// Evidence so far: HBM traffic is compulsory (R5 coop: FETCH 135 MB +
// WRITE 139 MB); ~160 µs of the timed window is harness re-poison fills;
// kernel-side budget ~94 µs vs ~55 µs floor. This round removes one
// dispatch + one launch gap + the part round-trip:
//  - C=64 chunks. Each scan_mul block computes its own chunk prefix from
//    the 2 MB part array (<=63 coalesced vf4 loads/thread, L2/L3-resident,
//    4-way tree sum to avoid a serial FADD chain).
//  - k1 unroll 16 for deeper load ILP at 512 blocks.
//  - out stores stay nontemporal so x remains L3-resident for the re-read.

typedef float vf4 __attribute__((ext_vector_type(4)));

constexpr int B = 8;
constexpr int T = 4096;
constexpr int D = 1024;
constexpr int C = 64;        // chunks along T
constexpr int L = T / C;     // 64 timesteps per chunk
constexpr int THREADS = 256; // 256 threads * float4 = 1024 = D

// part layout: part[(c*B + b)*D + d]  (coalesced in d for fixed (c,b))
// size = C*B*D*4 = 2 MiB of workspace.

// Kernel 1: per-chunk column sums. Block = one (b, chunk).
__global__ __launch_bounds__(THREADS)
void partial_sums(const float* __restrict__ x, float* __restrict__ part) {
    const int bc = blockIdx.x;
    const int b = bc / C;
    const int c = bc % C;
    const int d4 = threadIdx.x * 4;

    const float* px = x + ((size_t)(b * T + c * L)) * D + d4;
    vf4 acc = (vf4)(0.f);
#pragma unroll 16
    for (int t = 0; t < L; ++t)
        acc += *(const vf4*)(px + (size_t)t * D);
    *(vf4*)(part + ((size_t)c * B + b) * D + d4) = acc;
}

// Kernel 2: per-block chunk prefix from partials, then within-chunk
// exclusive scan + multiply, nontemporal store.
__global__ __launch_bounds__(THREADS)
void scan_mul(const float* __restrict__ x, const float* __restrict__ part,
              float* __restrict__ out) {
    const int bc = blockIdx.x;
    const int b = bc / C;
    const int c = bc % C;
    const int d4 = threadIdx.x * 4;

    // ---- chunk prefix: sum part[p][b][d4] over p < c, 4 independent chains
    vf4 s0 = (vf4)(0.f), s1 = (vf4)(0.f), s2 = (vf4)(0.f), s3 = (vf4)(0.f);
    {
        const float* pp = part + (size_t)b * D + d4;
        int p = 0;
        for (; p + 4 <= c; p += 4) {
            s0 += *(const vf4*)(pp + (size_t)(p + 0) * B * D);
            s1 += *(const vf4*)(pp + (size_t)(p + 1) * B * D);
            s2 += *(const vf4*)(pp + (size_t)(p + 2) * B * D);
            s3 += *(const vf4*)(pp + (size_t)(p + 3) * B * D);
        }
        for (; p < c; ++p)
            s0 += *(const vf4*)(pp + (size_t)p * B * D);
    }
    vf4 s = (s0 + s1) + (s2 + s3);

    // ---- within-chunk exclusive scan + multiply
    const size_t base = ((size_t)(b * T + c * L)) * D + d4;
#pragma unroll 8
    for (int t = 0; t < L; ++t) {
        vf4 v = *(const vf4*)(x + base + (size_t)t * D);
        vf4 o = v * s;
        s += v;
        __builtin_nontemporal_store(o, (vf4*)(out + base + (size_t)t * D));
    }
}

extern "C" void kernel_launch(void* const* d_in, const int* in_sizes, int n_in,
                              void* d_out, int out_size, void* d_ws, size_t ws_size,
                              hipStream_t stream) {
    const float* x = (const float*)d_in[0];
    float* out = (float*)d_out;
    float* part = (float*)d_ws; // C*B*D*4 = 2 MiB of scratch

    partial_sums<<<B * C, THREADS, 0, stream>>>(x, part);
    scan_mul<<<B * C, THREADS, 0, stream>>>(x, part, out);
}